// Round 15
// baseline (1361.275 us; speedup 1.0000x reference)
//
#include <hip/hip_runtime.h>
#include <hip/hip_bf16.h>

#define IMG 256
#define NPOS 65536

typedef __attribute__((ext_vector_type(8))) short short8;
typedef __attribute__((ext_vector_type(4))) float f32x4;

__device__ __forceinline__ float gelu_exact(float x){
  return 0.5f * x * (1.0f + erff(x * 0.7071067811865475f));
}

__device__ __forceinline__ short f2b(float x){
  __hip_bfloat16 hh = __float2bfloat16(x);
  short s;
  __builtin_memcpy(&s, &hh, sizeof(s));
  return s;
}

__device__ __forceinline__ float b2f(short s){
  unsigned int u = ((unsigned int)(unsigned short)s) << 16;
  float f;
  __builtin_memcpy(&f, &u, sizeof(f));
  return f;
}

template<int NWAVES>
__device__ __forceinline__ void block_reduce2(float& s, float& s2, float* red){
  __syncthreads();
  #pragma unroll
  for (int off=32; off>0; off>>=1){ s += __shfl_down(s, off); s2 += __shfl_down(s2, off); }
  int lane = threadIdx.x & 63, w = threadIdx.x >> 6;
  if (lane==0){ red[w*2]=s; red[w*2+1]=s2; }
  __syncthreads();
  if (threadIdx.x==0){
    float a=0.f, bb=0.f;
    #pragma unroll
    for (int i=0;i<NWAVES;i++){ a+=red[i*2]; bb+=red[i*2+1]; }
    red[2*NWAVES]=a; red[2*NWAVES+1]=bb;
  }
  __syncthreads();
  s=red[2*NWAVES]; s2=red[2*NWAVES+1];
}

// ---------------- W_CVT: f32 -> bf16 weights, once per launch ----------------
__global__ __launch_bounds__(1024) void w_cvt(
    const float* __restrict__ w0, const float* __restrict__ w1,
    const float* __restrict__ w2, const float* __restrict__ w3,
    const float* __restrict__ w4, const float* __restrict__ w5,
    short* __restrict__ outw)
{
  const int mi = blockIdx.y;
  const float* src = mi==0?w0: mi==1?w1: mi==2?w2: mi==3?w3: mi==4?w4: w5;
  const int i = blockIdx.x*1024 + threadIdx.x;
  outw[(size_t)mi*49152 + i] = f2b(src[i]);
}

// ============ K_AB: norm1 + CPE + qkv, wave = (window, group), NO barriers ======
__global__ __launch_bounds__(256) void k_ab(
    const float* __restrict__ y,
    const float* __restrict__ n1w, const float* __restrict__ n1b,
    const float* __restrict__ cw,  const float* __restrict__ cb,
    const float* __restrict__ cnw, const float* __restrict__ cnb,
    const short* __restrict__ qwB, const float* __restrict__ qb,
    const short* __restrict__ kwB, const float* __restrict__ kb,
    const short* __restrict__ vwB, const float* __restrict__ vb,
    short* __restrict__ qG, short* __restrict__ kG, short* __restrict__ vG,
    int win0)
{
  __shared__ char SMB[32768];
  const int t = threadIdx.x;
  const int w = t>>6, ln = t&63;
  const int bid = blockIdx.x;
  const int nwq = gridDim.x >> 3;
  const int wl  = (bid & 7) * nwq + (bid >> 3);   // XCD-contiguous windows
  const int win = win0 + wl;
  const int b = win>>10, W1=(win>>5)&31, W2=win&31;
  const size_t ybase = (size_t)b*768*(size_t)NPOS + (size_t)(W1*8)*IMG + (W2*8);
  const int g = blockIdx.y*4 + w;
  char* region = SMB + w*8192;   // this wave's ynT: [64 pos][128 B swizzled]

  // ---- phase 1: norm1 + CPE (lane = position, shuffle conv, conv x2) ----
  {
    const int p1 = ln>>3, p2 = ln&7;
    const bool up = p1>0, dn = p1<7, lt = p2>0, rt = p2<7;
    const float* yg = y + ybase + (size_t)(g*64)*NPOS + (size_t)p1*IMG + p2;
    const int swzofs = (ln&7)<<4;
    char* slotbase = region + ln*128;

    float s=0.f, s2=0.f;
    #pragma unroll
    for (int c0=0;c0<64;c0+=8){
      short8 pk;
      #pragma unroll
      for (int j=0;j<8;++j){
        float v = yg[(size_t)(c0+j)*NPOS];
        s += v; s2 += v*v;
        pk[j] = f2b(v);
      }
      *(short8*)(slotbase + ((c0*2) ^ swzofs)) = pk;
    }
    #pragma unroll
    for (int off=32; off>0; off>>=1){ s += __shfl_xor(s, off); s2 += __shfl_xor(s2, off); }
    const float mean = s * (1.f/4096.f);
    const float rstd = rsqrtf(s2*(1.f/4096.f) - mean*mean + 1e-5f);

    float sc=0.f, sc2=0.f;
    #pragma unroll 1
    for (int c0=0;c0<64;c0+=8){
      short8 y8 = *(const short8*)(slotbase + ((c0*2) ^ swzofs));
      #pragma unroll
      for (int j=0;j<8;++j){
        const int cg = g*64 + c0 + j;
        float a = n1w[cg]*rstd;
        float x = fmaf(b2f(y8[j]), a, n1b[cg] - mean*a);
        float nmm = __shfl(x, (ln-9)&63);
        float nm0 = __shfl(x, (ln-8)&63);
        float nmp = __shfl(x, (ln-7)&63);
        float n0m = __shfl(x, (ln-1)&63);
        float n0p = __shfl(x, (ln+1)&63);
        float npm = __shfl(x, (ln+7)&63);
        float np0 = __shfl(x, (ln+8)&63);
        float npp = __shfl(x, (ln+9)&63);
        const float* wp = cw + cg*9;
        float acc = cb[cg];
        acc = fmaf(wp[0], (up&&lt)?nmm:0.f, acc);
        acc = fmaf(wp[1], up?nm0:0.f, acc);
        acc = fmaf(wp[2], (up&&rt)?nmp:0.f, acc);
        acc = fmaf(wp[3], lt?n0m:0.f, acc);
        acc = fmaf(wp[4], x, acc);
        acc = fmaf(wp[5], rt?n0p:0.f, acc);
        acc = fmaf(wp[6], (dn&&lt)?npm:0.f, acc);
        acc = fmaf(wp[7], dn?np0:0.f, acc);
        acc = fmaf(wp[8], (dn&&rt)?npp:0.f, acc);
        sc += acc; sc2 += acc*acc;
      }
    }
    #pragma unroll
    for (int off=32; off>0; off>>=1){ sc += __shfl_xor(sc, off); sc2 += __shfl_xor(sc2, off); }
    const float mean2 = sc * (1.f/4096.f);
    const float rstd2 = rsqrtf(sc2*(1.f/4096.f) - mean2*mean2 + 1e-5f);

    #pragma unroll 1
    for (int c0=0;c0<64;c0+=8){
      short8 y8 = *(const short8*)(slotbase + ((c0*2) ^ swzofs));
      short8 o8;
      #pragma unroll
      for (int j=0;j<8;++j){
        const int cg = g*64 + c0 + j;
        float a = n1w[cg]*rstd;
        float x = fmaf(b2f(y8[j]), a, n1b[cg] - mean*a);
        float nmm = __shfl(x, (ln-9)&63);
        float nm0 = __shfl(x, (ln-8)&63);
        float nmp = __shfl(x, (ln-7)&63);
        float n0m = __shfl(x, (ln-1)&63);
        float n0p = __shfl(x, (ln+1)&63);
        float npm = __shfl(x, (ln+7)&63);
        float np0 = __shfl(x, (ln+8)&63);
        float npp = __shfl(x, (ln+9)&63);
        const float* wp = cw + cg*9;
        float acc = cb[cg];
        acc = fmaf(wp[0], (up&&lt)?nmm:0.f, acc);
        acc = fmaf(wp[1], up?nm0:0.f, acc);
        acc = fmaf(wp[2], (up&&rt)?nmp:0.f, acc);
        acc = fmaf(wp[3], lt?n0m:0.f, acc);
        acc = fmaf(wp[4], x, acc);
        acc = fmaf(wp[5], rt?n0p:0.f, acc);
        acc = fmaf(wp[6], (dn&&lt)?npm:0.f, acc);
        acc = fmaf(wp[7], dn?np0:0.f, acc);
        acc = fmaf(wp[8], (dn&&rt)?npp:0.f, acc);
        float f = (acc - mean2)*rstd2*cnw[cg] + cnb[cg];
        o8[j] = f2b(x + gelu_exact(f));
      }
      *(short8*)(slotbase + ((c0*2) ^ swzofs)) = o8;
    }
  }
  // no barrier: this wave reads only its own region

  // ---- phase 2: q/k/v GEMMs for this group ----
  const int l15 = ln&15, c4 = ln>>4, kb8 = c4*8, rbase = c4*4;
  #pragma unroll 1
  for (int mat=0; mat<3; ++mat){
    const short* WB = mat==0?qwB:(mat==1?kwB:vwB);
    const float* Bb = mat==0?qb:(mat==1?kb:vb);
    short* dst = mat==0?qG:(mat==1?kG:vG);
    short8 afr[4][2];
    float bias[4][4];
    #pragma unroll
    for (int mt2=0;mt2<4;++mt2){
      #pragma unroll
      for (int ks=0;ks<2;++ks)
        afr[mt2][ks] = *(const short8*)&WB[(size_t)(g*64+mt2*16+l15)*64 + ks*32 + kb8];
      #pragma unroll
      for (int r=0;r<4;++r)
        bias[mt2][r] = Bb[g*64 + mt2*16 + rbase + r];
    }
    #pragma unroll
    for (int nt=0;nt<4;++nt){
      const int pos = nt*16 + l15;
      short8 b0 = *(const short8*)(region + pos*128 + ((      kb8*2) ^ ((pos&7)<<4)));
      short8 b1 = *(const short8*)(region + pos*128 + ((64 + kb8*2) ^ ((pos&7)<<4)));
      #pragma unroll
      for (int mt2=0;mt2<4;++mt2){
        f32x4 acc = {0.f,0.f,0.f,0.f};
        acc = __builtin_amdgcn_mfma_f32_16x16x32_bf16(afr[mt2][0], b0, acc, 0,0,0);
        acc = __builtin_amdgcn_mfma_f32_16x16x32_bf16(afr[mt2][1], b1, acc, 0,0,0);
        #pragma unroll
        for (int r=0;r<4;++r){
          const int hh = rbase + r;      // head
          float val = acc[r] + bias[mt2][r];
          size_t addr = ((size_t)(wl*16 + hh)*48 + 4*g + mt2)*64 + pos;
          dst[addr] = f2b(mat==0 ? val * 0.14433756729740643f : val);
        }
      }
    }
  }
}

// ---------------- K_CP: fused attention + proj + residual + norm2 partials ----------
__global__ __launch_bounds__(1024) void k_cp(
    const short* __restrict__ qG, const short* __restrict__ kG,
    const short* __restrict__ vG,
    const float* __restrict__ y,
    const short* __restrict__ pwB, const float* __restrict__ pb,
    float* __restrict__ out, float* __restrict__ part, int win0)
{
  extern __shared__ short SM[];     // 65536 shorts = 128 KB
  const int t = threadIdx.x;
  const int h = t>>6, ln = t&63;
  const int bid = blockIdx.x;
  const int nwq = gridDim.x >> 3;
  const int wl  = (bid & 7) * nwq + (bid >> 3);   // XCD-contiguous windows
  const int win = win0 + wl;
  const int b = win>>10, W1=(win>>5)&31, W2=win&31;
  const size_t ybase = (size_t)b*768*(size_t)NPOS + (size_t)(W1*8)*IMG + (W2*8);
  const int l15 = ln&15, c4 = ln>>4, kb8 = c4*8, rbase = c4*4;
  const size_t hbase = (size_t)(wl*16+h)*48;
  short* R = SM + h*4096;           // wave-private 8 KB region

  short8 kf[3][2], qf[3][2];
  #pragma unroll
  for (int tt=0;tt<3;++tt)
    #pragma unroll
    for (int ks=0;ks<2;++ks){
      kf[tt][ks] = *(const short8*)&kG[(hbase + 16*tt + l15)*64 + ks*32 + kb8];
      qf[tt][ks] = *(const short8*)&qG[(hbase + 16*tt + l15)*64 + ks*32 + kb8];
    }
  f32x4 Su[6];
  const int DTa[6] = {0,1,1,2,2,2};
  const int ETa[6] = {0,0,1,0,1,2};
  #pragma unroll
  for (int u=0;u<6;++u){
    f32x4 acc = {0.f,0.f,0.f,0.f};
    acc = __builtin_amdgcn_mfma_f32_16x16x32_bf16(kf[ETa[u]][0], qf[DTa[u]][0], acc, 0,0,0);
    acc = __builtin_amdgcn_mfma_f32_16x16x32_bf16(kf[ETa[u]][1], qf[DTa[u]][1], acc, 0,0,0);
    Su[u] = acc;
  }

  float inv3[3];
  #pragma unroll
  for (int dt=0;dt<3;++dt){
    const int ub = (dt==0)?0:((dt==1)?1:3);
    float m = -1e30f;
    #pragma unroll
    for (int et=0; et<=dt; ++et)
      #pragma unroll
      for (int r=0;r<4;++r){
        bool valid = (et<dt) || ((rbase + r) <= (l15|3));
        if (valid) m = fmaxf(m, Su[ub+et][r]);
      }
    m = fmaxf(m, __shfl_xor(m,16));
    m = fmaxf(m, __shfl_xor(m,32));
    float sm = 0.f;
    #pragma unroll
    for (int et=0; et<=dt; ++et)
      #pragma unroll
      for (int r=0;r<4;++r){
        bool valid = (et<dt) || ((rbase + r) <= (l15|3));
        float p = valid ? expf(Su[ub+et][r] - m) : 0.f;
        Su[ub+et][r] = p; sm += p;
      }
    sm += __shfl_xor(sm,16);
    sm += __shfl_xor(sm,32);
    inv3[dt] = 1.f/sm;
  }

  short8 z8 = {0,0,0,0,0,0,0,0};
  #pragma unroll
  for (int nblk=0;nblk<8;++nblk){
    short8 v8 = z8;
    if (ln < 48) v8 = *(const short8*)&vG[(hbase + ln)*64 + nblk*8];
    #pragma unroll
    for (int j=0;j<8;++j){
      int n = nblk*8 + j;
      R[n*64 + (((ln>>3) ^ (n&7))<<3) + (ln&7)] = v8[j];
    }
  }
  short8 bv[4][2];
  #pragma unroll
  for (int nt=0;nt<4;++nt){
    const int n = 16*nt + l15;
    bv[nt][0] = *(const short8*)&R[n*64 + ((c4 ^ (n&7))<<3)];
    bv[nt][1] = *(const short8*)&R[n*64 + (((4+c4) ^ (n&7))<<3)];
  }

  #pragma unroll
  for (int i_=0;i_<6;++i_) *(short8*)&R[i_*512 + ln*8] = z8;
  #pragma unroll
  for (int dt=0;dt<3;++dt){
    const int ub = (dt==0)?0:((dt==1)?1:3);
    const int d = 16*dt + l15;
    #pragma unroll
    for (int et=0; et<=dt; ++et)
      #pragma unroll
      for (int r=0;r<4;++r){
        int e = 16*et + rbase + r;
        R[d*64 + (((e>>3) ^ (d&7))<<3) + (e&7)] = f2b(Su[ub+et][r]*inv3[dt]);
      }
  }
  short8 aP[4];
  const int PDT[4] = {0,1,2,2}, PKS[4] = {0,0,0,1};
  #pragma unroll
  for (int i_=0;i_<4;++i_){
    int d = 16*PDT[i_] + l15;
    int ch = PKS[i_]*4 + c4;
    aP[i_] = *(const short8*)&R[d*64 + ((ch ^ (d&7))<<3)];
  }

  __syncthreads();   // all LDS reads done; regions become O-buffer [g][n][ci]

  #pragma unroll
  for (int nt=0;nt<4;++nt){
    const int n = 16*nt + l15;
    f32x4 O0 = {0.f,0.f,0.f,0.f};
    f32x4 O1 = {0.f,0.f,0.f,0.f};
    f32x4 O2 = {0.f,0.f,0.f,0.f};
    O0 = __builtin_amdgcn_mfma_f32_16x16x32_bf16(aP[0], bv[nt][0], O0, 0,0,0);
    O1 = __builtin_amdgcn_mfma_f32_16x16x32_bf16(aP[1], bv[nt][0], O1, 0,0,0);
    O2 = __builtin_amdgcn_mfma_f32_16x16x32_bf16(aP[2], bv[nt][0], O2, 0,0,0);
    O2 = __builtin_amdgcn_mfma_f32_16x16x32_bf16(aP[3], bv[nt][1], O2, 0,0,0);
    #pragma unroll
    for (int r=0;r<4;++r){
      const int swz = (((2*r + (h>>3)) ^ (n&7))<<3) + (h&7);
      SM[(c4     )*4096 + n*64 + swz] = f2b(O0[r]);
      SM[(4 + c4 )*4096 + n*64 + swz] = f2b(O1[r]);
      SM[(8 + c4 )*4096 + n*64 + swz] = f2b(O2[r]);
    }
  }

  __syncthreads();

  #pragma unroll 1
  for (int j=0;j<3;++j){
    const int u = h*3 + j;
    const int g = u>>2, mt = u&3;
    short8 aw[2];
    float bi[4];
    #pragma unroll
    for (int ks=0;ks<2;++ks)
      aw[ks] = *(const short8*)&pwB[(size_t)(g*64 + mt*16 + l15)*64 + ks*32 + kb8];
    #pragma unroll
    for (int r=0;r<4;++r) bi[r] = pb[g*64 + mt*16 + rbase + r];

    f32x4 acc[4] = {};
    #pragma unroll
    for (int nt=0;nt<4;++nt){
      const int n = 16*nt + l15;
      short8 b0 = *(const short8*)&SM[g*4096 + n*64 + ((c4 ^ (n&7))<<3)];
      short8 b1 = *(const short8*)&SM[g*4096 + n*64 + (((4+c4) ^ (n&7))<<3)];
      acc[nt] = __builtin_amdgcn_mfma_f32_16x16x32_bf16(aw[0], b0, acc[nt], 0,0,0);
      acc[nt] = __builtin_amdgcn_mfma_f32_16x16x32_bf16(aw[1], b1, acc[nt], 0,0,0);
    }
    float s=0.f, s2=0.f;
    #pragma unroll
    for (int nt=0;nt<4;++nt){
      const int n = 16*nt + l15;
      const size_t rowoff = ybase + (size_t)(n>>3)*IMG + (n&7);
      #pragma unroll
      for (int r=0;r<4;++r){
        int m = mt*16 + rbase + r;
        size_t ad = rowoff + (size_t)(g*64+m)*NPOS;
        float o = y[ad] + bi[r] + acc[nt][r];
        out[ad] = o;
        s += o; s2 += o*o;
      }
    }
    #pragma unroll
    for (int off=32; off>0; off>>=1){ s += __shfl_xor(s, off); s2 += __shfl_xor(s2, off); }
    if (ln==0){
      size_t idx = ((size_t)(b*12+g)*1024 + (win&1023))*4 + mt;
      part[idx*2+0]=s; part[idx*2+1]=s2;
    }
  }
}

// ---------------- K3: finalize norm2 stats (deterministic) ----------------
__global__ __launch_bounds__(256) void k3_stats(
    const float* __restrict__ part, float* __restrict__ stats)
{
  const int bg = blockIdx.x;  // 0..23
  const int t = threadIdx.x;
  float s=0.f, s2=0.f;
  #pragma unroll
  for (int j=0;j<16;++j){
    size_t idx = (size_t)bg*4096 + t*16 + j;
    s  += part[idx*2+0];
    s2 += part[idx*2+1];
  }
  __shared__ float red[10];
  block_reduce2<4>(s,s2,red);
  if (t==0){
    const float Ninv = 1.f/(64.f*65536.f);
    float mean = s*Ninv;
    float var  = s2*Ninv - mean*mean;
    stats[bg*2+0] = mean;
    stats[bg*2+1] = rsqrtf(var + 1e-5f);
  }
}

// ---------------- K_D: norm2 + f1 + gelu + f2 + residual, wide-load wave-private ----
// grid (1024,12,2), 256 threads (4 waves); wave wv owns positions pt*64+wv*16..+15.
// io tile read ONCE via 4 coalesced float4 loads/wave into f32 LDS tile (pitch 17);
// all redistribution in LDS; residual read+writeback into same tile; 4 float4 stores.
__global__ __launch_bounds__(256) void k_d(
    const float* __restrict__ n2w, const float* __restrict__ n2b,
    const short* __restrict__ f1wB, const float* __restrict__ f1b,
    const short* __restrict__ f2wB, const float* __restrict__ f2bi,
    const float* __restrict__ stats, float* __restrict__ io)
{
  __shared__ float Tt[4][64*17];    // f32 tile per wave: [ch][pos], pitch 17
  __shared__ short Hh[4][64*17];    // h bf16 per wave: [m][pos], pitch 17
  const int t = threadIdx.x;
  const int pt = blockIdx.x, g = blockIdx.y, b = blockIdx.z;
  const int bg = b*12 + g;
  const float mean = stats[bg*2+0], rstd = stats[bg*2+1];
  const size_t base = ((size_t)(b*768 + g*64))*NPOS + (size_t)pt*64;

  const int wv = t>>6, ln = t&63;
  const int l15 = ln&15, c4 = ln>>4, kb8 = c4*8, rbase = c4*4;
  float* Tw = Tt[wv];
  short* Hw = Hh[wv];
  const int poff = wv*16;           // wave's global pos offset within the 64-tile

  // ---- load tile: 4 coalesced float4 instructions per wave ----
  {
    const int chl = ln>>2, q4 = (ln&3)*4;
    #pragma unroll
    for (int i=0;i<4;++i){
      const int ch = i*16 + chl;
      float4 v = *(const float4*)&io[base + (size_t)ch*NPOS + poff + q4];
      Tw[ch*17 + q4+0]=v.x; Tw[ch*17 + q4+1]=v.y;
      Tw[ch*17 + q4+2]=v.z; Tw[ch*17 + q4+3]=v.w;
    }
  }

  // ---- norm2 + bf16 pack: B-frags directly in regs (own pos = l15) ----
  short8 xb0, xb1;
  #pragma unroll
  for (int j=0;j<8;++j){
    const int ch0 = kb8 + j;
    float A0 = rstd*n2w[g*64+ch0];
    xb0[j] = f2b(fmaf(Tw[ch0*17 + l15], A0, n2b[g*64+ch0] - mean*A0));
    const int ch1 = 32 + kb8 + j;
    float A1 = rstd*n2w[g*64+ch1];
    xb1[j] = f2b(fmaf(Tw[ch1*17 + l15], A1, n2b[g*64+ch1] - mean*A1));
  }

  // ---- f1: 8 MFMAs ----
  f32x4 hacc[4];
  #pragma unroll
  for (int mt=0;mt<4;++mt){
    short8 a0 = *(const short8*)&f1wB[(size_t)(g*64+mt*16+l15)*64 + kb8];
    short8 a1 = *(const short8*)&f1wB[(size_t)(g*64+mt*16+l15)*64 + 32 + kb8];
    f32x4 acc = {0.f,0.f,0.f,0.f};
    acc = __builtin_amdgcn_mfma_f32_16x16x32_bf16(a0, xb0, acc, 0,0,0);
    acc = __builtin_amdgcn_mfma_f32_16x16x32_bf16(a1, xb1, acc, 0,0,0);
    hacc[mt] = acc;
  }

  // ---- gelu -> Hb (C layout: m = mt*16+rbase+r, pos = l15) ----
  #pragma unroll
  for (int mt=0;mt<4;++mt){
    #pragma unroll
    for (int r=0;r<4;++r){
      const int m = mt*16 + rbase + r;
      Hw[m*17 + l15] = f2b(gelu_exact(hacc[mt][r] + f1b[g*64+m]));
    }
  }

  // ---- Hb B-frags (wave-lockstep: all writes precede these reads) ----
  short8 hb0, hb1;
  #pragma unroll
  for (int j=0;j<8;++j){
    hb0[j] = Hw[(kb8+j)*17 + l15];
    hb1[j] = Hw[(32+kb8+j)*17 + l15];
  }

  // ---- f2: 8 MFMAs; residual read + writeback into tile ----
  #pragma unroll
  for (int mt=0;mt<4;++mt){
    short8 a0 = *(const short8*)&f2wB[(size_t)(g*64+mt*16+l15)*64 + kb8];
    short8 a1 = *(const short8*)&f2wB[(size_t)(g*64+mt*16+l15)*64 + 32 + kb8];
    f32x4 acc = {0.f,0.f,0.f,0.f};
    acc = __builtin_amdgcn_mfma_f32_16x16x32_bf16(a0, hb0, acc, 0,0,0);
    acc = __builtin_amdgcn_mfma_f32_16x16x32_bf16(a1, hb1, acc, 0,0,0);
    #pragma unroll
    for (int r=0;r<4;++r){
      const int m = mt*16 + rbase + r;
      Tw[m*17 + l15] = Tw[m*17 + l15] + acc[r] + f2bi[g*64+m];
    }
  }

  // ---- drain: 4 coalesced float4 stores per wave ----
  {
    const int chl = ln>>2, q4 = (ln&3)*4;
    #pragma unroll
    for (int i=0;i<4;++i){
      const int ch = i*16 + chl;
      float4 v;
      v.x = Tw[ch*17 + q4+0]; v.y = Tw[ch*17 + q4+1];
      v.z = Tw[ch*17 + q4+2]; v.w = Tw[ch*17 + q4+3];
      *(float4*)&io[base + (size_t)ch*NPOS + poff + q4] = v;
    }
  }
}

extern "C" void kernel_launch(void* const* d_in, const int* in_sizes, int n_in,
                              void* d_out, int out_size, void* d_ws, size_t ws_size,
                              hipStream_t stream){
  const float* y    = (const float*)d_in[0];
  const float* n1w  = (const float*)d_in[1];
  const float* n1b  = (const float*)d_in[2];
  const float* cw   = (const float*)d_in[3];
  const float* cb   = (const float*)d_in[4];
  const float* cnw  = (const float*)d_in[5];
  const float* cnb  = (const float*)d_in[6];
  const float* qw   = (const float*)d_in[7];
  const float* qb   = (const float*)d_in[8];
  const float* kw   = (const float*)d_in[9];
  const float* kb   = (const float*)d_in[10];
  const float* vw   = (const float*)d_in[11];
  const float* vb   = (const float*)d_in[12];
  const float* pw   = (const float*)d_in[13];
  const float* pb   = (const float*)d_in[14];
  const float* n2w  = (const float*)d_in[15];
  const float* n2b  = (const float*)d_in[16];
  const float* f1w  = (const float*)d_in[17];
  const float* f1b  = (const float*)d_in[18];
  const float* f2w  = (const float*)d_in[19];
  const float* f2b_ = (const float*)d_in[20];
  float* out   = (float*)d_out;

  unsigned char* wsb = (unsigned char*)d_ws;
  float* part  = (float*)wsb;                 // 786432 B
  float* stats = part + 24*1024*4*2;          // 48 f32
  short* wbf   = (short*)(wsb + 786624);      // 6 * 49152 bf16
  short* qwB  = wbf;
  short* kwB  = wbf + 49152;
  short* vwB  = wbf + 2*49152;
  short* pwB  = wbf + 3*49152;
  short* f1wB = wbf + 4*49152;
  short* f2wB = wbf + 5*49152;

  // chunking: 3 buffers (q, k, v); start at C=4 so per-chunk qkv stays L3-resident.
  int C = 32;
  {
    const int cand[4] = {4,8,16,32};
    for (int i=0;i<4;++i){
      int nw = 2048 / cand[i];
      size_t Y = (size_t)nw * 16 * 48 * 64 * 2;
      if ((size_t)(1<<21) + 3*Y <= ws_size){ C = cand[i]; break; }
    }
  }
  const int nw = 2048 / C;
  const size_t Y = (size_t)nw * 16 * 48 * 64 * 2;
  short* qG  = (short*)(wsb + (1<<21));
  short* kG  = (short*)(wsb + (1<<21) + Y);
  short* vG  = (short*)(wsb + (1<<21) + 2*Y);

  hipLaunchKernelGGL(w_cvt, dim3(48, 6), dim3(1024), 0, stream,
                     qw, kw, vw, pw, f1w, f2w, wbf);

  for (int c=0; c<C; ++c){
    int win0 = c * nw;
    hipLaunchKernelGGL(k_ab, dim3(nw, 3), dim3(256), 0, stream,
                       y, n1w,n1b, cw,cb, cnw,cnb,
                       qwB,qb, kwB,kb, vwB,vb,
                       qG, kG, vG, win0);
    hipLaunchKernelGGL(k_cp, dim3(nw), dim3(1024), 131072, stream,
                       qG, kG, vG, y, pwB, pb, out, part, win0);
  }
  hipLaunchKernelGGL(k3_stats, dim3(24), dim3(256), 0, stream, part, stats);
  hipLaunchKernelGGL(k_d, dim3(1024, 12, 2), dim3(256), 0, stream,
                     n2w,n2b, f1wB,f1b, f2wB,f2b_, stats, out);
}

// Round 16
// 1315.418 us; speedup vs baseline: 1.0349x; 1.0349x over previous
//
#include <hip/hip_runtime.h>
#include <hip/hip_bf16.h>

#define IMG 256
#define NPOS 65536

typedef __attribute__((ext_vector_type(8))) short short8;
typedef __attribute__((ext_vector_type(4))) float f32x4;

__device__ __forceinline__ float gelu_exact(float x){
  return 0.5f * x * (1.0f + erff(x * 0.7071067811865475f));
}

__device__ __forceinline__ short f2b(float x){
  __hip_bfloat16 hh = __float2bfloat16(x);
  short s;
  __builtin_memcpy(&s, &hh, sizeof(s));
  return s;
}

__device__ __forceinline__ float b2f(short s){
  unsigned int u = ((unsigned int)(unsigned short)s) << 16;
  float f;
  __builtin_memcpy(&f, &u, sizeof(f));
  return f;
}

template<int NWAVES>
__device__ __forceinline__ void block_reduce2(float& s, float& s2, float* red){
  __syncthreads();
  #pragma unroll
  for (int off=32; off>0; off>>=1){ s += __shfl_down(s, off); s2 += __shfl_down(s2, off); }
  int lane = threadIdx.x & 63, w = threadIdx.x >> 6;
  if (lane==0){ red[w*2]=s; red[w*2+1]=s2; }
  __syncthreads();
  if (threadIdx.x==0){
    float a=0.f, bb=0.f;
    #pragma unroll
    for (int i=0;i<NWAVES;i++){ a+=red[i*2]; bb+=red[i*2+1]; }
    red[2*NWAVES]=a; red[2*NWAVES+1]=bb;
  }
  __syncthreads();
  s=red[2*NWAVES]; s2=red[2*NWAVES+1];
}

// ---------------- W_CVT: f32 -> bf16 weights, once per launch ----------------
__global__ __launch_bounds__(1024) void w_cvt(
    const float* __restrict__ w0, const float* __restrict__ w1,
    const float* __restrict__ w2, const float* __restrict__ w3,
    const float* __restrict__ w4, const float* __restrict__ w5,
    short* __restrict__ outw)
{
  const int mi = blockIdx.y;
  const float* src = mi==0?w0: mi==1?w1: mi==2?w2: mi==3?w3: mi==4?w4: w5;
  const int i = blockIdx.x*1024 + threadIdx.x;
  outw[(size_t)mi*49152 + i] = f2b(src[i]);
}

// ============ K_AB: norm1 + CPE + qkv, wave = (window, group), NO barriers ======
__global__ __launch_bounds__(256) void k_ab(
    const float* __restrict__ y,
    const float* __restrict__ n1w, const float* __restrict__ n1b,
    const float* __restrict__ cw,  const float* __restrict__ cb,
    const float* __restrict__ cnw, const float* __restrict__ cnb,
    const short* __restrict__ qwB, const float* __restrict__ qb,
    const short* __restrict__ kwB, const float* __restrict__ kb,
    const short* __restrict__ vwB, const float* __restrict__ vb,
    short* __restrict__ qG, short* __restrict__ kG, short* __restrict__ vG,
    int win0)
{
  __shared__ char SMB[32768];
  const int t = threadIdx.x;
  const int w = t>>6, ln = t&63;
  const int bid = blockIdx.x;
  const int nwq = gridDim.x >> 3;
  const int wl  = (bid & 7) * nwq + (bid >> 3);   // XCD-contiguous windows
  const int win = win0 + wl;
  const int b = win>>10, W1=(win>>5)&31, W2=win&31;
  const size_t ybase = (size_t)b*768*(size_t)NPOS + (size_t)(W1*8)*IMG + (W2*8);
  const int g = blockIdx.y*4 + w;
  char* region = SMB + w*8192;   // this wave's ynT: [64 pos][128 B swizzled]

  // ---- phase 1: norm1 + CPE (lane = position, shuffle conv, conv x2) ----
  {
    const int p1 = ln>>3, p2 = ln&7;
    const bool up = p1>0, dn = p1<7, lt = p2>0, rt = p2<7;
    const float* yg = y + ybase + (size_t)(g*64)*NPOS + (size_t)p1*IMG + p2;
    const int swzofs = (ln&7)<<4;
    char* slotbase = region + ln*128;

    float s=0.f, s2=0.f;
    #pragma unroll
    for (int c0=0;c0<64;c0+=8){
      short8 pk;
      #pragma unroll
      for (int j=0;j<8;++j){
        float v = yg[(size_t)(c0+j)*NPOS];
        s += v; s2 += v*v;
        pk[j] = f2b(v);
      }
      *(short8*)(slotbase + ((c0*2) ^ swzofs)) = pk;
    }
    #pragma unroll
    for (int off=32; off>0; off>>=1){ s += __shfl_xor(s, off); s2 += __shfl_xor(s2, off); }
    const float mean = s * (1.f/4096.f);
    const float rstd = rsqrtf(s2*(1.f/4096.f) - mean*mean + 1e-5f);

    float sc=0.f, sc2=0.f;
    #pragma unroll 1
    for (int c0=0;c0<64;c0+=8){
      short8 y8 = *(const short8*)(slotbase + ((c0*2) ^ swzofs));
      #pragma unroll
      for (int j=0;j<8;++j){
        const int cg = g*64 + c0 + j;
        float a = n1w[cg]*rstd;
        float x = fmaf(b2f(y8[j]), a, n1b[cg] - mean*a);
        float nmm = __shfl(x, (ln-9)&63);
        float nm0 = __shfl(x, (ln-8)&63);
        float nmp = __shfl(x, (ln-7)&63);
        float n0m = __shfl(x, (ln-1)&63);
        float n0p = __shfl(x, (ln+1)&63);
        float npm = __shfl(x, (ln+7)&63);
        float np0 = __shfl(x, (ln+8)&63);
        float npp = __shfl(x, (ln+9)&63);
        const float* wp = cw + cg*9;
        float acc = cb[cg];
        acc = fmaf(wp[0], (up&&lt)?nmm:0.f, acc);
        acc = fmaf(wp[1], up?nm0:0.f, acc);
        acc = fmaf(wp[2], (up&&rt)?nmp:0.f, acc);
        acc = fmaf(wp[3], lt?n0m:0.f, acc);
        acc = fmaf(wp[4], x, acc);
        acc = fmaf(wp[5], rt?n0p:0.f, acc);
        acc = fmaf(wp[6], (dn&&lt)?npm:0.f, acc);
        acc = fmaf(wp[7], dn?np0:0.f, acc);
        acc = fmaf(wp[8], (dn&&rt)?npp:0.f, acc);
        sc += acc; sc2 += acc*acc;
      }
    }
    #pragma unroll
    for (int off=32; off>0; off>>=1){ sc += __shfl_xor(sc, off); sc2 += __shfl_xor(sc2, off); }
    const float mean2 = sc * (1.f/4096.f);
    const float rstd2 = rsqrtf(sc2*(1.f/4096.f) - mean2*mean2 + 1e-5f);

    #pragma unroll 1
    for (int c0=0;c0<64;c0+=8){
      short8 y8 = *(const short8*)(slotbase + ((c0*2) ^ swzofs));
      short8 o8;
      #pragma unroll
      for (int j=0;j<8;++j){
        const int cg = g*64 + c0 + j;
        float a = n1w[cg]*rstd;
        float x = fmaf(b2f(y8[j]), a, n1b[cg] - mean*a);
        float nmm = __shfl(x, (ln-9)&63);
        float nm0 = __shfl(x, (ln-8)&63);
        float nmp = __shfl(x, (ln-7)&63);
        float n0m = __shfl(x, (ln-1)&63);
        float n0p = __shfl(x, (ln+1)&63);
        float npm = __shfl(x, (ln+7)&63);
        float np0 = __shfl(x, (ln+8)&63);
        float npp = __shfl(x, (ln+9)&63);
        const float* wp = cw + cg*9;
        float acc = cb[cg];
        acc = fmaf(wp[0], (up&&lt)?nmm:0.f, acc);
        acc = fmaf(wp[1], up?nm0:0.f, acc);
        acc = fmaf(wp[2], (up&&rt)?nmp:0.f, acc);
        acc = fmaf(wp[3], lt?n0m:0.f, acc);
        acc = fmaf(wp[4], x, acc);
        acc = fmaf(wp[5], rt?n0p:0.f, acc);
        acc = fmaf(wp[6], (dn&&lt)?npm:0.f, acc);
        acc = fmaf(wp[7], dn?np0:0.f, acc);
        acc = fmaf(wp[8], (dn&&rt)?npp:0.f, acc);
        float f = (acc - mean2)*rstd2*cnw[cg] + cnb[cg];
        o8[j] = f2b(x + gelu_exact(f));
      }
      *(short8*)(slotbase + ((c0*2) ^ swzofs)) = o8;
    }
  }
  // no barrier: this wave reads only its own region

  // ---- phase 2: q/k/v GEMMs for this group ----
  const int l15 = ln&15, c4 = ln>>4, kb8 = c4*8, rbase = c4*4;
  #pragma unroll 1
  for (int mat=0; mat<3; ++mat){
    const short* WB = mat==0?qwB:(mat==1?kwB:vwB);
    const float* Bb = mat==0?qb:(mat==1?kb:vb);
    short* dst = mat==0?qG:(mat==1?kG:vG);
    short8 afr[4][2];
    float bias[4][4];
    #pragma unroll
    for (int mt2=0;mt2<4;++mt2){
      #pragma unroll
      for (int ks=0;ks<2;++ks)
        afr[mt2][ks] = *(const short8*)&WB[(size_t)(g*64+mt2*16+l15)*64 + ks*32 + kb8];
      #pragma unroll
      for (int r=0;r<4;++r)
        bias[mt2][r] = Bb[g*64 + mt2*16 + rbase + r];
    }
    #pragma unroll
    for (int nt=0;nt<4;++nt){
      const int pos = nt*16 + l15;
      short8 b0 = *(const short8*)(region + pos*128 + ((      kb8*2) ^ ((pos&7)<<4)));
      short8 b1 = *(const short8*)(region + pos*128 + ((64 + kb8*2) ^ ((pos&7)<<4)));
      #pragma unroll
      for (int mt2=0;mt2<4;++mt2){
        f32x4 acc = {0.f,0.f,0.f,0.f};
        acc = __builtin_amdgcn_mfma_f32_16x16x32_bf16(afr[mt2][0], b0, acc, 0,0,0);
        acc = __builtin_amdgcn_mfma_f32_16x16x32_bf16(afr[mt2][1], b1, acc, 0,0,0);
        #pragma unroll
        for (int r=0;r<4;++r){
          const int hh = rbase + r;      // head
          float val = acc[r] + bias[mt2][r];
          size_t addr = ((size_t)(wl*16 + hh)*48 + 4*g + mt2)*64 + pos;
          dst[addr] = f2b(mat==0 ? val * 0.14433756729740643f : val);
        }
      }
    }
  }
}

// ---------------- K_CP: fused attention + proj + residual + norm2 partials ----------
__global__ __launch_bounds__(1024) void k_cp(
    const short* __restrict__ qG, const short* __restrict__ kG,
    const short* __restrict__ vG,
    const float* __restrict__ y,
    const short* __restrict__ pwB, const float* __restrict__ pb,
    float* __restrict__ out, float* __restrict__ part, int win0)
{
  extern __shared__ short SM[];     // 65536 shorts = 128 KB
  const int t = threadIdx.x;
  const int h = t>>6, ln = t&63;
  const int bid = blockIdx.x;
  const int nwq = gridDim.x >> 3;
  const int wl  = (bid & 7) * nwq + (bid >> 3);   // XCD-contiguous windows
  const int win = win0 + wl;
  const int b = win>>10, W1=(win>>5)&31, W2=win&31;
  const size_t ybase = (size_t)b*768*(size_t)NPOS + (size_t)(W1*8)*IMG + (W2*8);
  const int l15 = ln&15, c4 = ln>>4, kb8 = c4*8, rbase = c4*4;
  const size_t hbase = (size_t)(wl*16+h)*48;
  short* R = SM + h*4096;           // wave-private 8 KB region

  short8 kf[3][2], qf[3][2];
  #pragma unroll
  for (int tt=0;tt<3;++tt)
    #pragma unroll
    for (int ks=0;ks<2;++ks){
      kf[tt][ks] = *(const short8*)&kG[(hbase + 16*tt + l15)*64 + ks*32 + kb8];
      qf[tt][ks] = *(const short8*)&qG[(hbase + 16*tt + l15)*64 + ks*32 + kb8];
    }
  f32x4 Su[6];
  const int DTa[6] = {0,1,1,2,2,2};
  const int ETa[6] = {0,0,1,0,1,2};
  #pragma unroll
  for (int u=0;u<6;++u){
    f32x4 acc = {0.f,0.f,0.f,0.f};
    acc = __builtin_amdgcn_mfma_f32_16x16x32_bf16(kf[ETa[u]][0], qf[DTa[u]][0], acc, 0,0,0);
    acc = __builtin_amdgcn_mfma_f32_16x16x32_bf16(kf[ETa[u]][1], qf[DTa[u]][1], acc, 0,0,0);
    Su[u] = acc;
  }

  float inv3[3];
  #pragma unroll
  for (int dt=0;dt<3;++dt){
    const int ub = (dt==0)?0:((dt==1)?1:3);
    float m = -1e30f;
    #pragma unroll
    for (int et=0; et<=dt; ++et)
      #pragma unroll
      for (int r=0;r<4;++r){
        bool valid = (et<dt) || ((rbase + r) <= (l15|3));
        if (valid) m = fmaxf(m, Su[ub+et][r]);
      }
    m = fmaxf(m, __shfl_xor(m,16));
    m = fmaxf(m, __shfl_xor(m,32));
    float sm = 0.f;
    #pragma unroll
    for (int et=0; et<=dt; ++et)
      #pragma unroll
      for (int r=0;r<4;++r){
        bool valid = (et<dt) || ((rbase + r) <= (l15|3));
        float p = valid ? expf(Su[ub+et][r] - m) : 0.f;
        Su[ub+et][r] = p; sm += p;
      }
    sm += __shfl_xor(sm,16);
    sm += __shfl_xor(sm,32);
    inv3[dt] = 1.f/sm;
  }

  short8 z8 = {0,0,0,0,0,0,0,0};
  #pragma unroll
  for (int nblk=0;nblk<8;++nblk){
    short8 v8 = z8;
    if (ln < 48) v8 = *(const short8*)&vG[(hbase + ln)*64 + nblk*8];
    #pragma unroll
    for (int j=0;j<8;++j){
      int n = nblk*8 + j;
      R[n*64 + (((ln>>3) ^ (n&7))<<3) + (ln&7)] = v8[j];
    }
  }
  short8 bv[4][2];
  #pragma unroll
  for (int nt=0;nt<4;++nt){
    const int n = 16*nt + l15;
    bv[nt][0] = *(const short8*)&R[n*64 + ((c4 ^ (n&7))<<3)];
    bv[nt][1] = *(const short8*)&R[n*64 + (((4+c4) ^ (n&7))<<3)];
  }

  #pragma unroll
  for (int i_=0;i_<6;++i_) *(short8*)&R[i_*512 + ln*8] = z8;
  #pragma unroll
  for (int dt=0;dt<3;++dt){
    const int ub = (dt==0)?0:((dt==1)?1:3);
    const int d = 16*dt + l15;
    #pragma unroll
    for (int et=0; et<=dt; ++et)
      #pragma unroll
      for (int r=0;r<4;++r){
        int e = 16*et + rbase + r;
        R[d*64 + (((e>>3) ^ (d&7))<<3) + (e&7)] = f2b(Su[ub+et][r]*inv3[dt]);
      }
  }
  short8 aP[4];
  const int PDT[4] = {0,1,2,2}, PKS[4] = {0,0,0,1};
  #pragma unroll
  for (int i_=0;i_<4;++i_){
    int d = 16*PDT[i_] + l15;
    int ch = PKS[i_]*4 + c4;
    aP[i_] = *(const short8*)&R[d*64 + ((ch ^ (d&7))<<3)];
  }

  __syncthreads();   // all LDS reads done; regions become O-buffer [g][n][ci]

  #pragma unroll
  for (int nt=0;nt<4;++nt){
    const int n = 16*nt + l15;
    f32x4 O0 = {0.f,0.f,0.f,0.f};
    f32x4 O1 = {0.f,0.f,0.f,0.f};
    f32x4 O2 = {0.f,0.f,0.f,0.f};
    O0 = __builtin_amdgcn_mfma_f32_16x16x32_bf16(aP[0], bv[nt][0], O0, 0,0,0);
    O1 = __builtin_amdgcn_mfma_f32_16x16x32_bf16(aP[1], bv[nt][0], O1, 0,0,0);
    O2 = __builtin_amdgcn_mfma_f32_16x16x32_bf16(aP[2], bv[nt][0], O2, 0,0,0);
    O2 = __builtin_amdgcn_mfma_f32_16x16x32_bf16(aP[3], bv[nt][1], O2, 0,0,0);
    #pragma unroll
    for (int r=0;r<4;++r){
      const int swz = (((2*r + (h>>3)) ^ (n&7))<<3) + (h&7);
      SM[(c4     )*4096 + n*64 + swz] = f2b(O0[r]);
      SM[(4 + c4 )*4096 + n*64 + swz] = f2b(O1[r]);
      SM[(8 + c4 )*4096 + n*64 + swz] = f2b(O2[r]);
    }
  }

  __syncthreads();

  #pragma unroll 1
  for (int j=0;j<3;++j){
    const int u = h*3 + j;
    const int g = u>>2, mt = u&3;
    short8 aw[2];
    float bi[4];
    #pragma unroll
    for (int ks=0;ks<2;++ks)
      aw[ks] = *(const short8*)&pwB[(size_t)(g*64 + mt*16 + l15)*64 + ks*32 + kb8];
    #pragma unroll
    for (int r=0;r<4;++r) bi[r] = pb[g*64 + mt*16 + rbase + r];

    f32x4 acc[4] = {};
    #pragma unroll
    for (int nt=0;nt<4;++nt){
      const int n = 16*nt + l15;
      short8 b0 = *(const short8*)&SM[g*4096 + n*64 + ((c4 ^ (n&7))<<3)];
      short8 b1 = *(const short8*)&SM[g*4096 + n*64 + (((4+c4) ^ (n&7))<<3)];
      acc[nt] = __builtin_amdgcn_mfma_f32_16x16x32_bf16(aw[0], b0, acc[nt], 0,0,0);
      acc[nt] = __builtin_amdgcn_mfma_f32_16x16x32_bf16(aw[1], b1, acc[nt], 0,0,0);
    }
    float s=0.f, s2=0.f;
    #pragma unroll
    for (int nt=0;nt<4;++nt){
      const int n = 16*nt + l15;
      const size_t rowoff = ybase + (size_t)(n>>3)*IMG + (n&7);
      #pragma unroll
      for (int r=0;r<4;++r){
        int m = mt*16 + rbase + r;
        size_t ad = rowoff + (size_t)(g*64+m)*NPOS;
        float o = y[ad] + bi[r] + acc[nt][r];
        out[ad] = o;
        s += o; s2 += o*o;
      }
    }
    #pragma unroll
    for (int off=32; off>0; off>>=1){ s += __shfl_xor(s, off); s2 += __shfl_xor(s2, off); }
    if (ln==0){
      size_t idx = ((size_t)(b*12+g)*1024 + (win&1023))*4 + mt;
      part[idx*2+0]=s; part[idx*2+1]=s2;
    }
  }
}

// ---------------- K3: finalize norm2 stats (deterministic) ----------------
__global__ __launch_bounds__(256) void k3_stats(
    const float* __restrict__ part, float* __restrict__ stats)
{
  const int bg = blockIdx.x;  // 0..23
  const int t = threadIdx.x;
  float s=0.f, s2=0.f;
  #pragma unroll
  for (int j=0;j<16;++j){
    size_t idx = (size_t)bg*4096 + t*16 + j;
    s  += part[idx*2+0];
    s2 += part[idx*2+1];
  }
  __shared__ float red[10];
  block_reduce2<4>(s,s2,red);
  if (t==0){
    const float Ninv = 1.f/(64.f*65536.f);
    float mean = s*Ninv;
    float var  = s2*Ninv - mean*mean;
    stats[bg*2+0] = mean;
    stats[bg*2+1] = rsqrtf(var + 1e-5f);
  }
}

// ---------------- K_D: norm2 + f1 + gelu + f2 + residual (MFMA, in-place) ----------
// (round-13 block version — best measured at 340 us)
__global__ __launch_bounds__(256) void k_d(
    const float* __restrict__ n2w, const float* __restrict__ n2b,
    const short* __restrict__ f1wB, const float* __restrict__ f1b,
    const short* __restrict__ f2wB, const float* __restrict__ f2bi,
    const float* __restrict__ stats, float* __restrict__ io)
{
  __shared__ short Xb[4096];
  __shared__ short Hb[4096];
  const int t = threadIdx.x;
  const int pt = blockIdx.x, g = blockIdx.y, b = blockIdx.z;
  const int bg = b*12 + g;
  const float mean = stats[bg*2+0], rstd = stats[bg*2+1];
  const size_t base = ((size_t)(b*768 + g*64))*NPOS + (size_t)pt*64;

  const int wv = t>>6, ln = t&63;
  const int l15 = ln&15, kb8 = (ln>>4)*8, rbase = (ln>>4)*4, c4 = ln>>4;
  const int n = wv*16 + l15;

  // prefetch final-residual values (store-phase mapping) — overlaps MFMA phases
  float res[16];
  #pragma unroll
  for (int mt=0;mt<4;++mt)
    #pragma unroll
    for (int r=0;r<4;++r)
      res[mt*4+r] = io[base + (size_t)(mt*16 + rbase + r)*NPOS + n];

  {
    const int pp = t>>3, posq = t&7;
    const int ch0 = pp*2;
    const float* p0 = io + base + (size_t)ch0*NPOS + posq*8;
    float4 x00 = *(const float4*)p0;
    float4 x01 = *(const float4*)(p0+4);
    const float* p1 = p0 + NPOS;
    float4 x10 = *(const float4*)p1;
    float4 x11 = *(const float4*)(p1+4);
    float A0 = rstd*n2w[g*64+ch0],   C0 = n2b[g*64+ch0]   - mean*A0;
    float A1 = rstd*n2w[g*64+ch0+1], C1 = n2b[g*64+ch0+1] - mean*A1;
    float va[8] = {x00.x,x00.y,x00.z,x00.w,x01.x,x01.y,x01.z,x01.w};
    float vb[8] = {x10.x,x10.y,x10.z,x10.w,x11.x,x11.y,x11.z,x11.w};
    #pragma unroll
    for (int j=0;j<8;++j){
      int pos = posq*8 + j;
      unsigned int u0 = (unsigned short)f2b(va[j]*A0 + C0);
      unsigned int u1 = (unsigned short)f2b(vb[j]*A1 + C1);
      *(unsigned int*)&Xb[pos*64 + (((ch0>>3) ^ (pos&7))<<3) + (ch0&7)] = u0 | (u1<<16);
    }
  }
  __syncthreads();

  short8 af[4][2];
  #pragma unroll
  for (int mt=0;mt<4;++mt)
    #pragma unroll
    for (int ks=0;ks<2;++ks)
      af[mt][ks] = *(const short8*)&f1wB[(size_t)(g*64 + mt*16 + l15)*64 + ks*32 + kb8];
  f32x4 h[4] = {};
  #pragma unroll
  for (int ks=0;ks<2;++ks){
    short8 bfr = *(const short8*)&Xb[n*64 + (((ks*4 + c4) ^ (n&7))<<3)];
    #pragma unroll
    for (int mt=0;mt<4;++mt)
      h[mt] = __builtin_amdgcn_mfma_f32_16x16x32_bf16(af[mt][ks], bfr, h[mt], 0,0,0);
  }
  #pragma unroll
  for (int mt=0;mt<4;++mt){
    #pragma unroll
    for (int rp=0;rp<4;rp+=2){
      int m = mt*16 + rbase + rp;
      float h0 = gelu_exact(h[mt][rp]   + f1b[g*64+m]);
      float h1 = gelu_exact(h[mt][rp+1] + f1b[g*64+m+1]);
      unsigned int u0 = (unsigned short)f2b(h0);
      unsigned int u1 = (unsigned short)f2b(h1);
      *(unsigned int*)&Hb[n*64 + (((m>>3) ^ (n&7))<<3) + (m&7)] = u0 | (u1<<16);
    }
  }
  __syncthreads();

  #pragma unroll
  for (int mt=0;mt<4;++mt)
    #pragma unroll
    for (int ks=0;ks<2;++ks)
      af[mt][ks] = *(const short8*)&f2wB[(size_t)(g*64 + mt*16 + l15)*64 + ks*32 + kb8];
  f32x4 o[4] = {};
  #pragma unroll
  for (int ks=0;ks<2;++ks){
    short8 bfr = *(const short8*)&Hb[n*64 + (((ks*4 + c4) ^ (n&7))<<3)];
    #pragma unroll
    for (int mt=0;mt<4;++mt)
      o[mt] = __builtin_amdgcn_mfma_f32_16x16x32_bf16(af[mt][ks], bfr, o[mt], 0,0,0);
  }
  #pragma unroll
  for (int mt=0;mt<4;++mt)
    #pragma unroll
    for (int r=0;r<4;++r){
      int m = mt*16 + rbase + r;
      io[base + (size_t)m*NPOS + n] = res[mt*4+r] + o[mt][r] + f2bi[g*64+m];
    }
}

extern "C" void kernel_launch(void* const* d_in, const int* in_sizes, int n_in,
                              void* d_out, int out_size, void* d_ws, size_t ws_size,
                              hipStream_t stream){
  const float* y    = (const float*)d_in[0];
  const float* n1w  = (const float*)d_in[1];
  const float* n1b  = (const float*)d_in[2];
  const float* cw   = (const float*)d_in[3];
  const float* cb   = (const float*)d_in[4];
  const float* cnw  = (const float*)d_in[5];
  const float* cnb  = (const float*)d_in[6];
  const float* qw   = (const float*)d_in[7];
  const float* qb   = (const float*)d_in[8];
  const float* kw   = (const float*)d_in[9];
  const float* kb   = (const float*)d_in[10];
  const float* vw   = (const float*)d_in[11];
  const float* vb   = (const float*)d_in[12];
  const float* pw   = (const float*)d_in[13];
  const float* pb   = (const float*)d_in[14];
  const float* n2w  = (const float*)d_in[15];
  const float* n2b  = (const float*)d_in[16];
  const float* f1w  = (const float*)d_in[17];
  const float* f1b  = (const float*)d_in[18];
  const float* f2w  = (const float*)d_in[19];
  const float* f2b_ = (const float*)d_in[20];
  float* out   = (float*)d_out;

  unsigned char* wsb = (unsigned char*)d_ws;
  float* part  = (float*)wsb;                 // 786432 B
  float* stats = part + 24*1024*4*2;          // 48 f32
  short* wbf   = (short*)(wsb + 786624);      // 6 * 49152 bf16
  short* qwB  = wbf;
  short* kwB  = wbf + 49152;
  short* vwB  = wbf + 2*49152;
  short* pwB  = wbf + 3*49152;
  short* f1wB = wbf + 4*49152;
  short* f2wB = wbf + 5*49152;

  // chunking: C=8 -> per-chunk working set (qkv 75MB + y 50MB + out 50MB) fits L3,
  // and k_cp grid = 256 blocks = exactly 1 per CU (C=16 would leave half idle).
  int C = 32;
  {
    const int cand[3] = {8,16,32};
    for (int i=0;i<3;++i){
      int nw = 2048 / cand[i];
      size_t Y = (size_t)nw * 16 * 48 * 64 * 2;
      if ((size_t)(1<<21) + 3*Y <= ws_size){ C = cand[i]; break; }
    }
  }
  const int nw = 2048 / C;
  const size_t Y = (size_t)nw * 16 * 48 * 64 * 2;
  short* qG  = (short*)(wsb + (1<<21));
  short* kG  = (short*)(wsb + (1<<21) + Y);
  short* vG  = (short*)(wsb + (1<<21) + 2*Y);

  hipLaunchKernelGGL(w_cvt, dim3(48, 6), dim3(1024), 0, stream,
                     qw, kw, vw, pw, f1w, f2w, wbf);

  for (int c=0; c<C; ++c){
    int win0 = c * nw;
    hipLaunchKernelGGL(k_ab, dim3(nw, 3), dim3(256), 0, stream,
                       y, n1w,n1b, cw,cb, cnw,cnb,
                       qwB,qb, kwB,kb, vwB,vb,
                       qG, kG, vG, win0);
    hipLaunchKernelGGL(k_cp, dim3(nw), dim3(1024), 131072, stream,
                       qG, kG, vG, y, pwB, pb, out, part, win0);
  }
  hipLaunchKernelGGL(k3_stats, dim3(24), dim3(256), 0, stream, part, stats);
  hipLaunchKernelGGL(k_d, dim3(1024, 12, 2), dim3(256), 0, stream,
                     n2w,n2b, f1wB,f1b, f2wB,f2b_, stats, out);
}

// Round 17
// 1304.978 us; speedup vs baseline: 1.0431x; 1.0080x over previous
//
#include <hip/hip_runtime.h>
#include <hip/hip_bf16.h>

#define IMG 256
#define NPOS 65536

typedef __attribute__((ext_vector_type(8))) short short8;
typedef __attribute__((ext_vector_type(4))) float f32x4;

__device__ __forceinline__ float gelu_exact(float x){
  return 0.5f * x * (1.0f + erff(x * 0.7071067811865475f));
}

__device__ __forceinline__ short f2b(float x){
  __hip_bfloat16 hh = __float2bfloat16(x);
  short s;
  __builtin_memcpy(&s, &hh, sizeof(s));
  return s;
}

__device__ __forceinline__ float b2f(short s){
  unsigned int u = ((unsigned int)(unsigned short)s) << 16;
  float f;
  __builtin_memcpy(&f, &u, sizeof(f));
  return f;
}

template<int NWAVES>
__device__ __forceinline__ void block_reduce2(float& s, float& s2, float* red){
  __syncthreads();
  #pragma unroll
  for (int off=32; off>0; off>>=1){ s += __shfl_down(s, off); s2 += __shfl_down(s2, off); }
  int lane = threadIdx.x & 63, w = threadIdx.x >> 6;
  if (lane==0){ red[w*2]=s; red[w*2+1]=s2; }
  __syncthreads();
  if (threadIdx.x==0){
    float a=0.f, bb=0.f;
    #pragma unroll
    for (int i=0;i<NWAVES;i++){ a+=red[i*2]; bb+=red[i*2+1]; }
    red[2*NWAVES]=a; red[2*NWAVES+1]=bb;
  }
  __syncthreads();
  s=red[2*NWAVES]; s2=red[2*NWAVES+1];
}

// ---------------- W_CVT: f32 -> bf16 weights, once per launch ----------------
__global__ __launch_bounds__(1024) void w_cvt(
    const float* __restrict__ w0, const float* __restrict__ w1,
    const float* __restrict__ w2, const float* __restrict__ w3,
    const float* __restrict__ w4, const float* __restrict__ w5,
    short* __restrict__ outw)
{
  const int mi = blockIdx.y;
  const float* src = mi==0?w0: mi==1?w1: mi==2?w2: mi==3?w3: mi==4?w4: w5;
  const int i = blockIdx.x*1024 + threadIdx.x;
  outw[(size_t)mi*49152 + i] = f2b(src[i]);
}

// ============ K_AB: norm1 + CPE + qkv, wave = (window, group), NO barriers ======
__global__ __launch_bounds__(256) void k_ab(
    const float* __restrict__ y,
    const float* __restrict__ n1w, const float* __restrict__ n1b,
    const float* __restrict__ cw,  const float* __restrict__ cb,
    const float* __restrict__ cnw, const float* __restrict__ cnb,
    const short* __restrict__ qwB, const float* __restrict__ qb,
    const short* __restrict__ kwB, const float* __restrict__ kb,
    const short* __restrict__ vwB, const float* __restrict__ vb,
    short* __restrict__ qG, short* __restrict__ kG, short* __restrict__ vG,
    int win0)
{
  __shared__ char SMB[32768];
  const int t = threadIdx.x;
  const int w = t>>6, ln = t&63;
  const int bid = blockIdx.x;
  const int nwq = gridDim.x >> 3;
  const int wl  = (bid & 7) * nwq + (bid >> 3);   // XCD-contiguous windows
  const int win = win0 + wl;
  const int b = win>>10, W1=(win>>5)&31, W2=win&31;
  const size_t ybase = (size_t)b*768*(size_t)NPOS + (size_t)(W1*8)*IMG + (W2*8);
  const int g = blockIdx.y*4 + w;
  char* region = SMB + w*8192;   // this wave's ynT: [64 pos][128 B swizzled]

  // ---- phase 1: norm1 + CPE (lane = position, shuffle conv, conv x2) ----
  {
    const int p1 = ln>>3, p2 = ln&7;
    const bool up = p1>0, dn = p1<7, lt = p2>0, rt = p2<7;
    const float* yg = y + ybase + (size_t)(g*64)*NPOS + (size_t)p1*IMG + p2;
    const int swzofs = (ln&7)<<4;
    char* slotbase = region + ln*128;

    float s=0.f, s2=0.f;
    #pragma unroll
    for (int c0=0;c0<64;c0+=8){
      short8 pk;
      #pragma unroll
      for (int j=0;j<8;++j){
        float v = yg[(size_t)(c0+j)*NPOS];
        s += v; s2 += v*v;
        pk[j] = f2b(v);
      }
      *(short8*)(slotbase + ((c0*2) ^ swzofs)) = pk;
    }
    #pragma unroll
    for (int off=32; off>0; off>>=1){ s += __shfl_xor(s, off); s2 += __shfl_xor(s2, off); }
    const float mean = s * (1.f/4096.f);
    const float rstd = rsqrtf(s2*(1.f/4096.f) - mean*mean + 1e-5f);

    float sc=0.f, sc2=0.f;
    #pragma unroll 1
    for (int c0=0;c0<64;c0+=8){
      short8 y8 = *(const short8*)(slotbase + ((c0*2) ^ swzofs));
      #pragma unroll
      for (int j=0;j<8;++j){
        const int cg = g*64 + c0 + j;
        float a = n1w[cg]*rstd;
        float x = fmaf(b2f(y8[j]), a, n1b[cg] - mean*a);
        float nmm = __shfl(x, (ln-9)&63);
        float nm0 = __shfl(x, (ln-8)&63);
        float nmp = __shfl(x, (ln-7)&63);
        float n0m = __shfl(x, (ln-1)&63);
        float n0p = __shfl(x, (ln+1)&63);
        float npm = __shfl(x, (ln+7)&63);
        float np0 = __shfl(x, (ln+8)&63);
        float npp = __shfl(x, (ln+9)&63);
        const float* wp = cw + cg*9;
        float acc = cb[cg];
        acc = fmaf(wp[0], (up&&lt)?nmm:0.f, acc);
        acc = fmaf(wp[1], up?nm0:0.f, acc);
        acc = fmaf(wp[2], (up&&rt)?nmp:0.f, acc);
        acc = fmaf(wp[3], lt?n0m:0.f, acc);
        acc = fmaf(wp[4], x, acc);
        acc = fmaf(wp[5], rt?n0p:0.f, acc);
        acc = fmaf(wp[6], (dn&&lt)?npm:0.f, acc);
        acc = fmaf(wp[7], dn?np0:0.f, acc);
        acc = fmaf(wp[8], (dn&&rt)?npp:0.f, acc);
        sc += acc; sc2 += acc*acc;
      }
    }
    #pragma unroll
    for (int off=32; off>0; off>>=1){ sc += __shfl_xor(sc, off); sc2 += __shfl_xor(sc2, off); }
    const float mean2 = sc * (1.f/4096.f);
    const float rstd2 = rsqrtf(sc2*(1.f/4096.f) - mean2*mean2 + 1e-5f);

    #pragma unroll 1
    for (int c0=0;c0<64;c0+=8){
      short8 y8 = *(const short8*)(slotbase + ((c0*2) ^ swzofs));
      short8 o8;
      #pragma unroll
      for (int j=0;j<8;++j){
        const int cg = g*64 + c0 + j;
        float a = n1w[cg]*rstd;
        float x = fmaf(b2f(y8[j]), a, n1b[cg] - mean*a);
        float nmm = __shfl(x, (ln-9)&63);
        float nm0 = __shfl(x, (ln-8)&63);
        float nmp = __shfl(x, (ln-7)&63);
        float n0m = __shfl(x, (ln-1)&63);
        float n0p = __shfl(x, (ln+1)&63);
        float npm = __shfl(x, (ln+7)&63);
        float np0 = __shfl(x, (ln+8)&63);
        float npp = __shfl(x, (ln+9)&63);
        const float* wp = cw + cg*9;
        float acc = cb[cg];
        acc = fmaf(wp[0], (up&&lt)?nmm:0.f, acc);
        acc = fmaf(wp[1], up?nm0:0.f, acc);
        acc = fmaf(wp[2], (up&&rt)?nmp:0.f, acc);
        acc = fmaf(wp[3], lt?n0m:0.f, acc);
        acc = fmaf(wp[4], x, acc);
        acc = fmaf(wp[5], rt?n0p:0.f, acc);
        acc = fmaf(wp[6], (dn&&lt)?npm:0.f, acc);
        acc = fmaf(wp[7], dn?np0:0.f, acc);
        acc = fmaf(wp[8], (dn&&rt)?npp:0.f, acc);
        float f = (acc - mean2)*rstd2*cnw[cg] + cnb[cg];
        o8[j] = f2b(x + gelu_exact(f));
      }
      *(short8*)(slotbase + ((c0*2) ^ swzofs)) = o8;
    }
  }
  // no barrier: this wave reads only its own region

  // ---- phase 2: q/k/v GEMMs for this group ----
  const int l15 = ln&15, c4 = ln>>4, kb8 = c4*8, rbase = c4*4;
  #pragma unroll 1
  for (int mat=0; mat<3; ++mat){
    const short* WB = mat==0?qwB:(mat==1?kwB:vwB);
    const float* Bb = mat==0?qb:(mat==1?kb:vb);
    short* dst = mat==0?qG:(mat==1?kG:vG);
    short8 afr[4][2];
    float bias[4][4];
    #pragma unroll
    for (int mt2=0;mt2<4;++mt2){
      #pragma unroll
      for (int ks=0;ks<2;++ks)
        afr[mt2][ks] = *(const short8*)&WB[(size_t)(g*64+mt2*16+l15)*64 + ks*32 + kb8];
      #pragma unroll
      for (int r=0;r<4;++r)
        bias[mt2][r] = Bb[g*64 + mt2*16 + rbase + r];
    }
    #pragma unroll
    for (int nt=0;nt<4;++nt){
      const int pos = nt*16 + l15;
      short8 b0 = *(const short8*)(region + pos*128 + ((      kb8*2) ^ ((pos&7)<<4)));
      short8 b1 = *(const short8*)(region + pos*128 + ((64 + kb8*2) ^ ((pos&7)<<4)));
      #pragma unroll
      for (int mt2=0;mt2<4;++mt2){
        f32x4 acc = {0.f,0.f,0.f,0.f};
        acc = __builtin_amdgcn_mfma_f32_16x16x32_bf16(afr[mt2][0], b0, acc, 0,0,0);
        acc = __builtin_amdgcn_mfma_f32_16x16x32_bf16(afr[mt2][1], b1, acc, 0,0,0);
        #pragma unroll
        for (int r=0;r<4;++r){
          const int hh = rbase + r;      // head
          float val = acc[r] + bias[mt2][r];
          size_t addr = ((size_t)(wl*16 + hh)*48 + 4*g + mt2)*64 + pos;
          dst[addr] = f2b(mat==0 ? val * 0.14433756729740643f : val);
        }
      }
    }
  }
}

// ---------------- K_CP: fused attention + proj + residual + norm2 partials ----------
__global__ __launch_bounds__(1024) void k_cp(
    const short* __restrict__ qG, const short* __restrict__ kG,
    const short* __restrict__ vG,
    const float* __restrict__ y,
    const short* __restrict__ pwB, const float* __restrict__ pb,
    float* __restrict__ out, float* __restrict__ part, int win0)
{
  extern __shared__ short SM[];     // 65536 shorts = 128 KB
  const int t = threadIdx.x;
  const int h = t>>6, ln = t&63;
  const int bid = blockIdx.x;
  const int nwq = gridDim.x >> 3;
  const int wl  = (bid & 7) * nwq + (bid >> 3);   // XCD-contiguous windows
  const int win = win0 + wl;
  const int b = win>>10, W1=(win>>5)&31, W2=win&31;
  const size_t ybase = (size_t)b*768*(size_t)NPOS + (size_t)(W1*8)*IMG + (W2*8);
  const int l15 = ln&15, c4 = ln>>4, kb8 = c4*8, rbase = c4*4;
  const size_t hbase = (size_t)(wl*16+h)*48;
  short* R = SM + h*4096;           // wave-private 8 KB region

  short8 kf[3][2], qf[3][2];
  #pragma unroll
  for (int tt=0;tt<3;++tt)
    #pragma unroll
    for (int ks=0;ks<2;++ks){
      kf[tt][ks] = *(const short8*)&kG[(hbase + 16*tt + l15)*64 + ks*32 + kb8];
      qf[tt][ks] = *(const short8*)&qG[(hbase + 16*tt + l15)*64 + ks*32 + kb8];
    }
  f32x4 Su[6];
  const int DTa[6] = {0,1,1,2,2,2};
  const int ETa[6] = {0,0,1,0,1,2};
  #pragma unroll
  for (int u=0;u<6;++u){
    f32x4 acc = {0.f,0.f,0.f,0.f};
    acc = __builtin_amdgcn_mfma_f32_16x16x32_bf16(kf[ETa[u]][0], qf[DTa[u]][0], acc, 0,0,0);
    acc = __builtin_amdgcn_mfma_f32_16x16x32_bf16(kf[ETa[u]][1], qf[DTa[u]][1], acc, 0,0,0);
    Su[u] = acc;
  }

  float inv3[3];
  #pragma unroll
  for (int dt=0;dt<3;++dt){
    const int ub = (dt==0)?0:((dt==1)?1:3);
    float m = -1e30f;
    #pragma unroll
    for (int et=0; et<=dt; ++et)
      #pragma unroll
      for (int r=0;r<4;++r){
        bool valid = (et<dt) || ((rbase + r) <= (l15|3));
        if (valid) m = fmaxf(m, Su[ub+et][r]);
      }
    m = fmaxf(m, __shfl_xor(m,16));
    m = fmaxf(m, __shfl_xor(m,32));
    float sm = 0.f;
    #pragma unroll
    for (int et=0; et<=dt; ++et)
      #pragma unroll
      for (int r=0;r<4;++r){
        bool valid = (et<dt) || ((rbase + r) <= (l15|3));
        float p = valid ? expf(Su[ub+et][r] - m) : 0.f;
        Su[ub+et][r] = p; sm += p;
      }
    sm += __shfl_xor(sm,16);
    sm += __shfl_xor(sm,32);
    inv3[dt] = 1.f/sm;
  }

  short8 z8 = {0,0,0,0,0,0,0,0};
  #pragma unroll
  for (int nblk=0;nblk<8;++nblk){
    short8 v8 = z8;
    if (ln < 48) v8 = *(const short8*)&vG[(hbase + ln)*64 + nblk*8];
    #pragma unroll
    for (int j=0;j<8;++j){
      int n = nblk*8 + j;
      R[n*64 + (((ln>>3) ^ (n&7))<<3) + (ln&7)] = v8[j];
    }
  }
  short8 bv[4][2];
  #pragma unroll
  for (int nt=0;nt<4;++nt){
    const int n = 16*nt + l15;
    bv[nt][0] = *(const short8*)&R[n*64 + ((c4 ^ (n&7))<<3)];
    bv[nt][1] = *(const short8*)&R[n*64 + (((4+c4) ^ (n&7))<<3)];
  }

  #pragma unroll
  for (int i_=0;i_<6;++i_) *(short8*)&R[i_*512 + ln*8] = z8;
  #pragma unroll
  for (int dt=0;dt<3;++dt){
    const int ub = (dt==0)?0:((dt==1)?1:3);
    const int d = 16*dt + l15;
    #pragma unroll
    for (int et=0; et<=dt; ++et)
      #pragma unroll
      for (int r=0;r<4;++r){
        int e = 16*et + rbase + r;
        R[d*64 + (((e>>3) ^ (d&7))<<3) + (e&7)] = f2b(Su[ub+et][r]*inv3[dt]);
      }
  }
  short8 aP[4];
  const int PDT[4] = {0,1,2,2}, PKS[4] = {0,0,0,1};
  #pragma unroll
  for (int i_=0;i_<4;++i_){
    int d = 16*PDT[i_] + l15;
    int ch = PKS[i_]*4 + c4;
    aP[i_] = *(const short8*)&R[d*64 + ((ch ^ (d&7))<<3)];
  }

  __syncthreads();   // all LDS reads done; regions become O-buffer [g][n][ci]

  #pragma unroll
  for (int nt=0;nt<4;++nt){
    const int n = 16*nt + l15;
    f32x4 O0 = {0.f,0.f,0.f,0.f};
    f32x4 O1 = {0.f,0.f,0.f,0.f};
    f32x4 O2 = {0.f,0.f,0.f,0.f};
    O0 = __builtin_amdgcn_mfma_f32_16x16x32_bf16(aP[0], bv[nt][0], O0, 0,0,0);
    O1 = __builtin_amdgcn_mfma_f32_16x16x32_bf16(aP[1], bv[nt][0], O1, 0,0,0);
    O2 = __builtin_amdgcn_mfma_f32_16x16x32_bf16(aP[2], bv[nt][0], O2, 0,0,0);
    O2 = __builtin_amdgcn_mfma_f32_16x16x32_bf16(aP[3], bv[nt][1], O2, 0,0,0);
    #pragma unroll
    for (int r=0;r<4;++r){
      const int swz = (((2*r + (h>>3)) ^ (n&7))<<3) + (h&7);
      SM[(c4     )*4096 + n*64 + swz] = f2b(O0[r]);
      SM[(4 + c4 )*4096 + n*64 + swz] = f2b(O1[r]);
      SM[(8 + c4 )*4096 + n*64 + swz] = f2b(O2[r]);
    }
  }

  __syncthreads();

  #pragma unroll 1
  for (int j=0;j<3;++j){
    const int u = h*3 + j;
    const int g = u>>2, mt = u&3;
    short8 aw[2];
    float bi[4];
    #pragma unroll
    for (int ks=0;ks<2;++ks)
      aw[ks] = *(const short8*)&pwB[(size_t)(g*64 + mt*16 + l15)*64 + ks*32 + kb8];
    #pragma unroll
    for (int r=0;r<4;++r) bi[r] = pb[g*64 + mt*16 + rbase + r];

    f32x4 acc[4] = {};
    #pragma unroll
    for (int nt=0;nt<4;++nt){
      const int n = 16*nt + l15;
      short8 b0 = *(const short8*)&SM[g*4096 + n*64 + ((c4 ^ (n&7))<<3)];
      short8 b1 = *(const short8*)&SM[g*4096 + n*64 + (((4+c4) ^ (n&7))<<3)];
      acc[nt] = __builtin_amdgcn_mfma_f32_16x16x32_bf16(aw[0], b0, acc[nt], 0,0,0);
      acc[nt] = __builtin_amdgcn_mfma_f32_16x16x32_bf16(aw[1], b1, acc[nt], 0,0,0);
    }
    float s=0.f, s2=0.f;
    #pragma unroll
    for (int nt=0;nt<4;++nt){
      const int n = 16*nt + l15;
      const size_t rowoff = ybase + (size_t)(n>>3)*IMG + (n&7);
      #pragma unroll
      for (int r=0;r<4;++r){
        int m = mt*16 + rbase + r;
        size_t ad = rowoff + (size_t)(g*64+m)*NPOS;
        float o = y[ad] + bi[r] + acc[nt][r];
        out[ad] = o;
        s += o; s2 += o*o;
      }
    }
    #pragma unroll
    for (int off=32; off>0; off>>=1){ s += __shfl_xor(s, off); s2 += __shfl_xor(s2, off); }
    if (ln==0){
      size_t idx = ((size_t)(b*12+g)*1024 + (win&1023))*4 + mt;
      part[idx*2+0]=s; part[idx*2+1]=s2;
    }
  }
}

// ---------------- K3: finalize norm2 stats (deterministic) ----------------
__global__ __launch_bounds__(256) void k3_stats(
    const float* __restrict__ part, float* __restrict__ stats)
{
  const int bg = blockIdx.x;  // 0..23
  const int t = threadIdx.x;
  float s=0.f, s2=0.f;
  #pragma unroll
  for (int j=0;j<16;++j){
    size_t idx = (size_t)bg*4096 + t*16 + j;
    s  += part[idx*2+0];
    s2 += part[idx*2+1];
  }
  __shared__ float red[10];
  block_reduce2<4>(s,s2,red);
  if (t==0){
    const float Ninv = 1.f/(64.f*65536.f);
    float mean = s*Ninv;
    float var  = s2*Ninv - mean*mean;
    stats[bg*2+0] = mean;
    stats[bg*2+1] = rsqrtf(var + 1e-5f);
  }
}

// ---------------- K_D: norm2 + f1 + gelu + f2 + residual (MFMA, in-place) ----------
// r13 block version + XCD-contiguous pt swizzle + removed Hb barrier (wave-local cols)
__global__ __launch_bounds__(256) void k_d(
    const float* __restrict__ n2w, const float* __restrict__ n2b,
    const short* __restrict__ f1wB, const float* __restrict__ f1b,
    const short* __restrict__ f2wB, const float* __restrict__ f2bi,
    const float* __restrict__ stats, float* __restrict__ io)
{
  __shared__ short Xb[4096];
  __shared__ short Hb[4096];
  const int t = threadIdx.x;
  const int bid = blockIdx.x;
  const int ptq = gridDim.x >> 3;
  const int pt = (bid & 7) * ptq + (bid >> 3);   // XCD-contiguous tiles
  const int g = blockIdx.y, b = blockIdx.z;
  const int bg = b*12 + g;
  const float mean = stats[bg*2+0], rstd = stats[bg*2+1];
  const size_t base = ((size_t)(b*768 + g*64))*NPOS + (size_t)pt*64;

  const int wv = t>>6, ln = t&63;
  const int l15 = ln&15, kb8 = (ln>>4)*8, rbase = (ln>>4)*4, c4 = ln>>4;
  const int n = wv*16 + l15;

  // prefetch final-residual values (store-phase mapping) — overlaps MFMA phases
  float res[16];
  #pragma unroll
  for (int mt=0;mt<4;++mt)
    #pragma unroll
    for (int r=0;r<4;++r)
      res[mt*4+r] = io[base + (size_t)(mt*16 + rbase + r)*NPOS + n];

  {
    const int pp = t>>3, posq = t&7;
    const int ch0 = pp*2;
    const float* p0 = io + base + (size_t)ch0*NPOS + posq*8;
    float4 x00 = *(const float4*)p0;
    float4 x01 = *(const float4*)(p0+4);
    const float* p1 = p0 + NPOS;
    float4 x10 = *(const float4*)p1;
    float4 x11 = *(const float4*)(p1+4);
    float A0 = rstd*n2w[g*64+ch0],   C0 = n2b[g*64+ch0]   - mean*A0;
    float A1 = rstd*n2w[g*64+ch0+1], C1 = n2b[g*64+ch0+1] - mean*A1;
    float va[8] = {x00.x,x00.y,x00.z,x00.w,x01.x,x01.y,x01.z,x01.w};
    float vb[8] = {x10.x,x10.y,x10.z,x10.w,x11.x,x11.y,x11.z,x11.w};
    #pragma unroll
    for (int j=0;j<8;++j){
      int pos = posq*8 + j;
      unsigned int u0 = (unsigned short)f2b(va[j]*A0 + C0);
      unsigned int u1 = (unsigned short)f2b(vb[j]*A1 + C1);
      *(unsigned int*)&Xb[pos*64 + (((ch0>>3) ^ (pos&7))<<3) + (ch0&7)] = u0 | (u1<<16);
    }
  }
  __syncthreads();   // Xb written cross-wave

  short8 af[4][2];
  #pragma unroll
  for (int mt=0;mt<4;++mt)
    #pragma unroll
    for (int ks=0;ks<2;++ks)
      af[mt][ks] = *(const short8*)&f1wB[(size_t)(g*64 + mt*16 + l15)*64 + ks*32 + kb8];
  f32x4 h[4] = {};
  #pragma unroll
  for (int ks=0;ks<2;++ks){
    short8 bfr = *(const short8*)&Xb[n*64 + (((ks*4 + c4) ^ (n&7))<<3)];
    #pragma unroll
    for (int mt=0;mt<4;++mt)
      h[mt] = __builtin_amdgcn_mfma_f32_16x16x32_bf16(af[mt][ks], bfr, h[mt], 0,0,0);
  }
  #pragma unroll
  for (int mt=0;mt<4;++mt){
    #pragma unroll
    for (int rp=0;rp<4;rp+=2){
      int m = mt*16 + rbase + rp;
      float h0 = gelu_exact(h[mt][rp]   + f1b[g*64+m]);
      float h1 = gelu_exact(h[mt][rp+1] + f1b[g*64+m+1]);
      unsigned int u0 = (unsigned short)f2b(h0);
      unsigned int u1 = (unsigned short)f2b(h1);
      *(unsigned int*)&Hb[n*64 + (((m>>3) ^ (n&7))<<3) + (m&7)] = u0 | (u1<<16);
    }
  }
  // no barrier: Hb row n (= wv*16+l15) written and read only by this wave's lanes

  #pragma unroll
  for (int mt=0;mt<4;++mt)
    #pragma unroll
    for (int ks=0;ks<2;++ks)
      af[mt][ks] = *(const short8*)&f2wB[(size_t)(g*64 + mt*16 + l15)*64 + ks*32 + kb8];
  f32x4 o[4] = {};
  #pragma unroll
  for (int ks=0;ks<2;++ks){
    short8 bfr = *(const short8*)&Hb[n*64 + (((ks*4 + c4) ^ (n&7))<<3)];
    #pragma unroll
    for (int mt=0;mt<4;++mt)
      o[mt] = __builtin_amdgcn_mfma_f32_16x16x32_bf16(af[mt][ks], bfr, o[mt], 0,0,0);
  }
  #pragma unroll
  for (int mt=0;mt<4;++mt)
    #pragma unroll
    for (int r=0;r<4;++r){
      int m = mt*16 + rbase + r;
      io[base + (size_t)m*NPOS + n] = res[mt*4+r] + o[mt][r] + f2bi[g*64+m];
    }
}

extern "C" void kernel_launch(void* const* d_in, const int* in_sizes, int n_in,
                              void* d_out, int out_size, void* d_ws, size_t ws_size,
                              hipStream_t stream){
  const float* y    = (const float*)d_in[0];
  const float* n1w  = (const float*)d_in[1];
  const float* n1b  = (const float*)d_in[2];
  const float* cw   = (const float*)d_in[3];
  const float* cb   = (const float*)d_in[4];
  const float* cnw  = (const float*)d_in[5];
  const float* cnb  = (const float*)d_in[6];
  const float* qw   = (const float*)d_in[7];
  const float* qb   = (const float*)d_in[8];
  const float* kw   = (const float*)d_in[9];
  const float* kb   = (const float*)d_in[10];
  const float* vw   = (const float*)d_in[11];
  const float* vb   = (const float*)d_in[12];
  const float* pw   = (const float*)d_in[13];
  const float* pb   = (const float*)d_in[14];
  const float* n2w  = (const float*)d_in[15];
  const float* n2b  = (const float*)d_in[16];
  const float* f1w  = (const float*)d_in[17];
  const float* f1b  = (const float*)d_in[18];
  const float* f2w  = (const float*)d_in[19];
  const float* f2b_ = (const float*)d_in[20];
  float* out   = (float*)d_out;

  unsigned char* wsb = (unsigned char*)d_ws;
  float* part  = (float*)wsb;                 // 786432 B
  float* stats = part + 24*1024*4*2;          // 48 f32
  short* wbf   = (short*)(wsb + 786624);      // 6 * 49152 bf16
  short* qwB  = wbf;
  short* kwB  = wbf + 49152;
  short* vwB  = wbf + 2*49152;
  short* pwB  = wbf + 3*49152;
  short* f1wB = wbf + 4*49152;
  short* f2wB = wbf + 5*49152;

  // chunking: C=8 -> per-chunk working set fits L3; k_cp grid = 256 = 1 block/CU.
  int C = 32;
  {
    const int cand[3] = {8,16,32};
    for (int i=0;i<3;++i){
      int nw = 2048 / cand[i];
      size_t Y = (size_t)nw * 16 * 48 * 64 * 2;
      if ((size_t)(1<<21) + 3*Y <= ws_size){ C = cand[i]; break; }
    }
  }
  const int nw = 2048 / C;
  const size_t Y = (size_t)nw * 16 * 48 * 64 * 2;
  short* qG  = (short*)(wsb + (1<<21));
  short* kG  = (short*)(wsb + (1<<21) + Y);
  short* vG  = (short*)(wsb + (1<<21) + 2*Y);

  hipLaunchKernelGGL(w_cvt, dim3(48, 6), dim3(1024), 0, stream,
                     qw, kw, vw, pw, f1w, f2w, wbf);

  for (int c=0; c<C; ++c){
    int win0 = c * nw;
    hipLaunchKernelGGL(k_ab, dim3(nw, 3), dim3(256), 0, stream,
                       y, n1w,n1b, cw,cb, cnw,cnb,
                       qwB,qb, kwB,kb, vwB,vb,
                       qG, kG, vG, win0);
    hipLaunchKernelGGL(k_cp, dim3(nw), dim3(1024), 131072, stream,
                       qG, kG, vG, y, pwB, pb, out, part, win0);
  }
  hipLaunchKernelGGL(k3_stats, dim3(24), dim3(256), 0, stream, part, stats);
  hipLaunchKernelGGL(k_d, dim3(1024, 12, 2), dim3(256), 0, stream,
                     n2w,n2b, f1wB,f1b, f2wB,f2b_, stats, out);
}